// Round 8
// baseline (279.393 us; speedup 1.0000x reference)
//
#include <hip/hip_runtime.h>

// MHA: B=4 S=2048 D=1024 H=16 DH=64. Full bf16-MFMA pipeline (fp32 accum).

#define Bn  4
#define Sn  2048
#define Dn  1024
#define Hn  16
#define DHn 64
#define Mn  (Bn*Sn)          // 8192 rows
#define LDKV 72              // attn V LDS row stride (ushorts)

typedef unsigned short u16;
typedef __attribute__((ext_vector_type(8))) short short8;   // 8 x bf16 (4 VGPRs)
typedef __attribute__((ext_vector_type(4))) short short4v;  // 4 x bf16 (2 VGPRs)
typedef __attribute__((ext_vector_type(4))) float f32x4;    // MFMA C/D frag
typedef __attribute__((ext_vector_type(2))) unsigned int uint2v;
typedef __attribute__((ext_vector_type(4))) unsigned int uint4v;

__device__ __forceinline__ u16 f2bf(float f) {
  unsigned u = __float_as_uint(f);
  return (u16)((u + 0x7FFFu + ((u >> 16) & 1u)) >> 16);   // RNE
}

// async 16B/lane global->LDS DMA; lds dest = wave-uniform base + lane*16
__device__ __forceinline__ void async16(const void* g, void* l) {
  __builtin_amdgcn_global_load_lds(
      (const __attribute__((address_space(1))) void*)g,
      (__attribute__((address_space(3))) void*)l, 16, 0, 0);
}

// pack 2 fp32 -> 2 bf16 (truncation) in one v_perm_b32
__device__ __forceinline__ unsigned pk2(float a, float b) {
  return __builtin_amdgcn_perm(__float_as_uint(b), __float_as_uint(a), 0x07060302u);
}

// ---------------- convert: x (f32) -> xb (bf16) ----------------
__global__ __launch_bounds__(256) void k_convert_x(
    const float4* __restrict__ x, ushort4* __restrict__ xb, int n4) {
  int i = blockIdx.x * 256 + threadIdx.x;
  if (i < n4) {
    float4 f = x[i];
    ushort4 o;
    o.x = f2bf(f.x); o.y = f2bf(f.y); o.z = f2bf(f.z); o.w = f2bf(f.w);
    xb[i] = o;
  }
}

// ---- convert+transpose weights to [N][K] bf16 via LDS 64x64 tiles ----
__global__ __launch_bounds__(256) void k_convert_w(
    const float* __restrict__ Wq, const float* __restrict__ Wk,
    const float* __restrict__ Wv, const float* __restrict__ Wo,
    u16* __restrict__ WqT, u16* __restrict__ WkT,
    u16* __restrict__ WvT, u16* __restrict__ WoT) {
  __shared__ float t[64][65];
  const int bid = blockIdx.x;          // 0..1023
  const int wsel = bid >> 8;           // 0..3
  const int idx = bid & 255;
  const int tid = threadIdx.x;
  const int c = tid & 63;
  const int r4 = tid >> 6;             // 0..3

  if (wsel < 3) {
    const float* W = (wsel == 0) ? Wq : (wsel == 1) ? Wk : Wv;
    u16* T = (wsel == 0) ? WqT : (wsel == 1) ? WkT : WvT;
    const int h = idx >> 4;
    const int d0 = (idx & 15) * 64;
    const float* src = W + (size_t)h * (Dn * DHn) + (size_t)d0 * DHn;
#pragma unroll
    for (int r = 0; r < 16; r++) {
      int row = r * 4 + r4;
      t[row][c] = src[row * DHn + c];
    }
    __syncthreads();
    u16* dst = T + (size_t)(h * 64) * Dn + d0;
#pragma unroll
    for (int r = 0; r < 16; r++) {
      int erow = r * 4 + r4;
      dst[(size_t)erow * Dn + c] = f2bf(t[c][erow]);
    }
  } else {
    const int n0 = (idx >> 4) * 64;
    const int d0 = (idx & 15) * 64;
#pragma unroll
    for (int r = 0; r < 16; r++) {
      int row = r * 4 + r4;
      t[row][c] = Wo[(size_t)(d0 + row) * Dn + n0 + c];
    }
    __syncthreads();
#pragma unroll
    for (int r = 0; r < 16; r++) {
      int nrow = r * 4 + r4;
      WoT[(size_t)(n0 + nrow) * Dn + d0 + c] = f2bf(t[c][nrow]);
    }
  }
}

// ---------------- QKV projection GEMM body: 512 thr / 8 waves, 128x128 tile ----------------
template<int SWAP>
__device__ __forceinline__ void qkv_body(
    u16* As, u16* Bs, const u16* __restrict__ A, const u16* __restrict__ BT,
    const float* __restrict__ bias, u16* __restrict__ dst, float scale,
    int tile_m, int tile_n) {
  const int K = Dn;
  const int tid = threadIdx.x;
  const int lane = tid & 63;
  const int wave = tid >> 6;                    // 0..7
  const int wm = wave & 3, wn = wave >> 2;
  const int quad = lane >> 4, l16 = lane & 15;
  const int srow8 = lane >> 3;
  const int gchunk = (lane & 7) ^ srow8;
  const int sw = l16 & 7;

  f32x4 acc[2][4];
#pragma unroll
  for (int i = 0; i < 2; i++)
#pragma unroll
    for (int j = 0; j < 4; j++) acc[i][j] = (f32x4){0.f, 0.f, 0.f, 0.f};

  for (int k0 = 0; k0 < K; k0 += 64) {
    const int rb = wave * 16;
    async16(&A[(size_t)(tile_m + rb + srow8) * K + k0 + gchunk * 8], &As[rb * 64]);
    async16(&A[(size_t)(tile_m + rb + 8 + srow8) * K + k0 + gchunk * 8], &As[(rb + 8) * 64]);
    async16(&BT[(size_t)(tile_n + rb + srow8) * K + k0 + gchunk * 8], &Bs[rb * 64]);
    async16(&BT[(size_t)(tile_n + rb + 8 + srow8) * K + k0 + gchunk * 8], &Bs[(rb + 8) * 64]);
    __syncthreads();
#pragma unroll
    for (int ks = 0; ks < 2; ++ks) {
      short8 a[2], b[4];
#pragma unroll
      for (int i = 0; i < 2; i++)
        a[i] = *(const short8*)&As[(wm * 32 + i * 16 + l16) * 64 + ((ks * 4 + quad) ^ sw) * 8];
#pragma unroll
      for (int j = 0; j < 4; j++)
        b[j] = *(const short8*)&Bs[(wn * 64 + j * 16 + l16) * 64 + ((ks * 4 + quad) ^ sw) * 8];
#pragma unroll
      for (int i = 0; i < 2; i++)
#pragma unroll
        for (int j = 0; j < 4; j++)
          acc[i][j] = SWAP
              ? __builtin_amdgcn_mfma_f32_16x16x32_bf16(b[j], a[i], acc[i][j], 0, 0, 0)
              : __builtin_amdgcn_mfma_f32_16x16x32_bf16(a[i], b[j], acc[i][j], 0, 0, 0);
    }
    __syncthreads();
  }

  if (SWAP) {
#pragma unroll
    for (int i = 0; i < 2; i++) {
      const int s = tile_m + wm * 32 + i * 16 + l16;
      const int bb = s >> 11, sl = s & 2047;
#pragma unroll
      for (int j = 0; j < 4; j++) {
        const int nb = tile_n + wn * 64 + j * 16 + quad * 4;
        const float4 b4 = *(const float4*)&bias[nb];
        const int h = nb >> 6, e0 = nb & 63;
        ushort4 o;
        o.x = f2bf((acc[i][j][0] + b4.x) * scale);
        o.y = f2bf((acc[i][j][1] + b4.y) * scale);
        o.z = f2bf((acc[i][j][2] + b4.z) * scale);
        o.w = f2bf((acc[i][j][3] + b4.w) * scale);
        *(ushort4*)&dst[((size_t)(bb * Hn + h) * Sn + sl) * DHn + e0] = o;
      }
    }
  } else {
#pragma unroll
    for (int i = 0; i < 2; i++) {
      const int s0 = tile_m + wm * 32 + i * 16 + quad * 4;
      const int bb = s0 >> 11, sl = s0 & 2047;
#pragma unroll
      for (int j = 0; j < 4; j++) {
        const int n = tile_n + wn * 64 + j * 16 + l16;
        const int h = n >> 6, e = n & 63;
        const float bn = bias[n];
        ushort4 o;
        o.x = f2bf(acc[i][j][0] + bn);
        o.y = f2bf(acc[i][j][1] + bn);
        o.z = f2bf(acc[i][j][2] + bn);
        o.w = f2bf(acc[i][j][3] + bn);
        *(ushort4*)&dst[((size_t)(bb * Hn + h) * DHn + e) * Sn + sl] = o;
      }
    }
  }
}

// single dispatch, z = 0(q) / 1(k) / 2(v); both epilogue styles preserved
__global__ __launch_bounds__(512) void k_gemm_qkv(
    const u16* __restrict__ A, const u16* __restrict__ WqT,
    const u16* __restrict__ WkT, const u16* __restrict__ WvT,
    const float* __restrict__ bq, const float* __restrict__ bk,
    const float* __restrict__ bv, u16* __restrict__ qb,
    u16* __restrict__ kb, u16* __restrict__ vtb) {
  __shared__ u16 As[128 * 64];
  __shared__ u16 Bs[128 * 64];
  const int tile_m = blockIdx.x * 128;
  const int tile_n = blockIdx.y * 128;
  const int z = blockIdx.z;
  if (z == 2) {
    qkv_body<0>(As, Bs, A, WvT, bv, vtb, 1.0f, tile_m, tile_n);
  } else if (z == 1) {
    qkv_body<1>(As, Bs, A, WkT, bk, kb, 1.0f, tile_m, tile_n);
  } else {
    qkv_body<1>(As, Bs, A, WqT, bq, qb, 0.18033688011112042f, tile_m, tile_n);
  }
}

// ---------------- flash attention (R6 + ones-MFMA lr) ----------------
// 4 waves x 32 q-rows, 64 keys/tile, XCD-local block decode, key-permuted K
// staging (R6-verified: PV = 16x 16x16x32 MFMA, in-lane A-fragment).
// NEW: lr accumulated by mfma(apv, ones) -> octl; C-layout puts lr for q-row
// g2*16+quad*4+r in reg r of every lane that stores that row. Removes 24 VALU
// adds/tile and the entire epilogue shuffle reduction.
__global__ __launch_bounds__(256) void k_attn(
    const u16* __restrict__ qg, const u16* __restrict__ kg,
    const u16* __restrict__ vg, u16* __restrict__ ctx) {
  const int p = blockIdx.x;                         // 0..1023
  const int logical = (p & 7) * 128 + (p >> 3);     // same-bh blocks -> same XCD
  const int bh = logical >> 4;
  const int b = bh >> 4, h = bh & 15;
  const int tid = threadIdx.x;
  const int wave = tid >> 6, lane = tid & 63;
  const int quad = lane >> 4, l16 = lane & 15;
  const int qbase = (logical & 15) * 128 + wave * 32;

  const u16* qp = qg + (size_t)bh * Sn * DHn;
  const u16* kp = kg + (size_t)bh * Sn * DHn;
  const u16* vp = vg + (size_t)bh * DHn * Sn;   // [DH][S]

  __shared__ u16 Ks[2][64 * 64];
  __shared__ u16 Vs[2][64 * LDKV];

  const int srow8 = lane >> 3;
  const int gchunk = (lane & 7) ^ srow8;
  const int sw = l16 & 7;

  const int vrow = tid >> 3;
  const int vc = tid & 7;

  // permuted key indices for this lane's two staged K rows (loop-invariant)
  const int r0 = wave * 16 + srow8;
  const int r1 = r0 + 8;
  const int pk0 = ((r0 >> 5) << 5) | (((r0 >> 2) & 3) << 3) | ((r0 & 16) >> 2) | (r0 & 3);
  const int pk1 = ((r1 >> 5) << 5) | (((r1 >> 2) & 3) << 3) | ((r1 & 16) >> 2) | (r1 & 3);

  short8 bq[2][2];
#pragma unroll
  for (int g2 = 0; g2 < 2; g2++) {
    bq[g2][0] = *(const short8*)&qp[(size_t)(qbase + g2 * 16 + l16) * DHn + quad * 8];
    bq[g2][1] = *(const short8*)&qp[(size_t)(qbase + g2 * 16 + l16) * DHn + 32 + quad * 8];
  }

  f32x4 octx[2][4];
#pragma unroll
  for (int g2 = 0; g2 < 2; g2++)
#pragma unroll
    for (int j = 0; j < 4; j++) octx[g2][j] = (f32x4){0.f, 0.f, 0.f, 0.f};
  f32x4 octl[2];
  octl[0] = (f32x4){0.f, 0.f, 0.f, 0.f};
  octl[1] = (f32x4){0.f, 0.f, 0.f, 0.f};
  const short8 vones = {(short)0x3F80, (short)0x3F80, (short)0x3F80, (short)0x3F80,
                        (short)0x3F80, (short)0x3F80, (short)0x3F80, (short)0x3F80};

  {
    const int rbase = wave * 16;
    async16(&kp[(size_t)pk0 * DHn + gchunk * 8], &Ks[0][rbase * 64]);
    async16(&kp[(size_t)pk1 * DHn + gchunk * 8], &Ks[0][(rbase + 8) * 64]);
    uint4 vv0 = *(const uint4*)&vp[(size_t)vrow * Sn + vc * 8];
    uint4 vv1 = *(const uint4*)&vp[(size_t)(32 + vrow) * Sn + vc * 8];
    *(uint4*)&Vs[0][vrow * LDKV + vc * 8] = vv0;
    *(uint4*)&Vs[0][(32 + vrow) * LDKV + vc * 8] = vv1;
  }
  __syncthreads();

  uint4 vv0, vv1;
  for (int kt = 0; kt < Sn / 64; ++kt) {
    const int cur = kt & 1, nxt = cur ^ 1;
    const bool more = (kt + 1 < Sn / 64);
    if (more) {
      const int key1 = (kt + 1) * 64;
      const int rbase = wave * 16;
      async16(&kp[(size_t)(key1 + pk0) * DHn + gchunk * 8], &Ks[nxt][rbase * 64]);
      async16(&kp[(size_t)(key1 + pk1) * DHn + gchunk * 8], &Ks[nxt][(rbase + 8) * 64]);
      vv0 = *(const uint4*)&vp[(size_t)vrow * Sn + key1 + vc * 8];
      vv1 = *(const uint4*)&vp[(size_t)(32 + vrow) * Sn + key1 + vc * 8];
    }

    // QK^T + exp2 + pack; groups g = 2P + half fill apv[g2][P] halves in-lane
    uint4v apv[2][2];
#pragma unroll
    for (int g = 0; g < 4; g++) {
      short8 ka0 = *(const short8*)&Ks[cur][(g * 16 + l16) * 64 + (quad ^ sw) * 8];
      short8 ka1 = *(const short8*)&Ks[cur][(g * 16 + l16) * 64 + ((quad + 4) ^ sw) * 8];
#pragma unroll
      for (int g2 = 0; g2 < 2; g2++) {
        f32x4 sc = (f32x4){0.f, 0.f, 0.f, 0.f};
        sc = __builtin_amdgcn_mfma_f32_16x16x32_bf16(ka0, bq[g2][0], sc, 0, 0, 0);
        sc = __builtin_amdgcn_mfma_f32_16x16x32_bf16(ka1, bq[g2][1], sc, 0, 0, 0);
        float p4[4];
#pragma unroll
        for (int r = 0; r < 4; r++) p4[r] = __builtin_amdgcn_exp2f(sc[r]);
        apv[g2][g >> 1][(g & 1) * 2]     = pk2(p4[0], p4[1]);
        apv[g2][g >> 1][(g & 1) * 2 + 1] = pk2(p4[2], p4[3]);
      }
    }

    // lr via ones-B MFMA (4x) + PV: 16x 16x16x32 MFMA, B = V short8 (b128)
#pragma unroll
    for (int P = 0; P < 2; P++) {
      octl[0] = __builtin_amdgcn_mfma_f32_16x16x32_bf16(
          __builtin_bit_cast(short8, apv[0][P]), vones, octl[0], 0, 0, 0);
      octl[1] = __builtin_amdgcn_mfma_f32_16x16x32_bf16(
          __builtin_bit_cast(short8, apv[1][P]), vones, octl[1], 0, 0, 0);
    }
#pragma unroll
    for (int j = 0; j < 4; j++) {
#pragma unroll
      for (int P = 0; P < 2; P++) {
        short8 vb = *(const short8*)&Vs[cur][(j * 16 + l16) * LDKV + P * 32 + quad * 8];
        octx[0][j] = __builtin_amdgcn_mfma_f32_16x16x32_bf16(
            __builtin_bit_cast(short8, apv[0][P]), vb, octx[0][j], 0, 0, 0);
        octx[1][j] = __builtin_amdgcn_mfma_f32_16x16x32_bf16(
            __builtin_bit_cast(short8, apv[1][P]), vb, octx[1][j], 0, 0, 0);
      }
    }

    if (more) {
      *(uint4*)&Vs[nxt][vrow * LDKV + vc * 8] = vv0;
      *(uint4*)&Vs[nxt][(32 + vrow) * LDKV + vc * 8] = vv1;
    }
    __syncthreads();
  }

  // octl[g2][r] = lr for q-row qbase + g2*16 + quad*4 + r (same in all l16)
  float rl[2][4];
#pragma unroll
  for (int g2 = 0; g2 < 2; g2++)
#pragma unroll
    for (int r = 0; r < 4; r++)
      rl[g2][r] = 1.0f / octl[g2][r];

#pragma unroll
  for (int g2 = 0; g2 < 2; g2++)
#pragma unroll
    for (int j = 0; j < 4; j++) {
      const int n = h * DHn + j * 16 + l16;
#pragma unroll
      for (int r = 0; r < 4; r++) {
        const int s = qbase + g2 * 16 + quad * 4 + r;
        ctx[(size_t)(b * Sn + s) * Dn + n] = f2bf(octx[g2][j][r] * rl[g2][r]);
      }
    }
}

// ---------------- output projection GEMM: 512 thr / 8 waves, swapped epilogue ----------------
__global__ __launch_bounds__(512) void k_gemm_out(
    const u16* __restrict__ A, const u16* __restrict__ WoT,
    const float* __restrict__ bo, float* __restrict__ out) {
  const int tile_m = blockIdx.x * 128;
  const int tile_n = blockIdx.y * 128;
  const int K = Dn;

  __shared__ u16 As[128 * 64];
  __shared__ u16 Bs[128 * 64];

  const int tid = threadIdx.x;
  const int lane = tid & 63;
  const int wave = tid >> 6;
  const int wm = wave & 3, wn = wave >> 2;
  const int quad = lane >> 4, l16 = lane & 15;
  const int srow8 = lane >> 3;
  const int gchunk = (lane & 7) ^ srow8;
  const int sw = l16 & 7;

  f32x4 acc[2][4];
#pragma unroll
  for (int i = 0; i < 2; i++)
#pragma unroll
    for (int j = 0; j < 4; j++) acc[i][j] = (f32x4){0.f, 0.f, 0.f, 0.f};

  for (int k0 = 0; k0 < K; k0 += 64) {
    const int rb = wave * 16;
    async16(&A[(size_t)(tile_m + rb + srow8) * K + k0 + gchunk * 8], &As[rb * 64]);
    async16(&A[(size_t)(tile_m + rb + 8 + srow8) * K + k0 + gchunk * 8], &As[(rb + 8) * 64]);
    async16(&WoT[(size_t)(tile_n + rb + srow8) * K + k0 + gchunk * 8], &Bs[rb * 64]);
    async16(&WoT[(size_t)(tile_n + rb + 8 + srow8) * K + k0 + gchunk * 8], &Bs[(rb + 8) * 64]);
    __syncthreads();
#pragma unroll
    for (int ks = 0; ks < 2; ++ks) {
      short8 a[2], b[4];
#pragma unroll
      for (int i = 0; i < 2; i++)
        a[i] = *(const short8*)&As[(wm * 32 + i * 16 + l16) * 64 + ((ks * 4 + quad) ^ sw) * 8];
#pragma unroll
      for (int j = 0; j < 4; j++)
        b[j] = *(const short8*)&Bs[(wn * 64 + j * 16 + l16) * 64 + ((ks * 4 + quad) ^ sw) * 8];
#pragma unroll
      for (int i = 0; i < 2; i++)
#pragma unroll
        for (int j = 0; j < 4; j++)
          acc[i][j] = __builtin_amdgcn_mfma_f32_16x16x32_bf16(b[j], a[i], acc[i][j], 0, 0, 0);
    }
    __syncthreads();
  }

#pragma unroll
  for (int i = 0; i < 2; i++) {
    const int s = tile_m + wm * 32 + i * 16 + l16;
#pragma unroll
    for (int j = 0; j < 4; j++) {
      const int nb = tile_n + wn * 64 + j * 16 + quad * 4;
      const float4 b4 = *(const float4*)&bo[nb];
      float4 o;
      o.x = acc[i][j][0] + b4.x;
      o.y = acc[i][j][1] + b4.y;
      o.z = acc[i][j][2] + b4.z;
      o.w = acc[i][j][3] + b4.w;
      *(float4*)&out[(size_t)s * Dn + nb] = o;
    }
  }
}

extern "C" void kernel_launch(void* const* d_in, const int* in_sizes, int n_in,
                              void* d_out, int out_size, void* d_ws, size_t ws_size,
                              hipStream_t stream) {
  const float* x  = (const float*)d_in[0];
  const float* Wq = (const float*)d_in[1];
  const float* bq = (const float*)d_in[2];
  const float* Wk = (const float*)d_in[3];
  const float* bk = (const float*)d_in[4];
  const float* Wv = (const float*)d_in[5];
  const float* bv = (const float*)d_in[6];
  const float* Wo = (const float*)d_in[7];
  const float* bo = (const float*)d_in[8];
  float* out = (float*)d_out;

  // workspace carve-up (ctx aliases xb: xb dead after k_gemm_qkv) — ~75.5 MB
  char* ws = (char*)d_ws;
  u16* xb  = (u16*)ws;  ws += (size_t)Mn * Dn * 2;
  u16* WqT = (u16*)ws;  ws += (size_t)Dn * Dn * 2;
  u16* WkT = (u16*)ws;  ws += (size_t)Dn * Dn * 2;
  u16* WvT = (u16*)ws;  ws += (size_t)Dn * Dn * 2;
  u16* WoT = (u16*)ws;  ws += (size_t)Dn * Dn * 2;
  u16* qb  = (u16*)ws;  ws += (size_t)Mn * Dn * 2;
  u16* kb  = (u16*)ws;  ws += (size_t)Mn * Dn * 2;
  u16* vtb = (u16*)ws;  ws += (size_t)Mn * Dn * 2;
  u16* ctx = xb;        // alias

  k_convert_x<<<(Mn * Dn / 4) / 256, 256, 0, stream>>>((const float4*)x, (ushort4*)xb, Mn * Dn / 4);
  k_convert_w<<<1024, 256, 0, stream>>>(Wq, Wk, Wv, Wo, WqT, WkT, WvT, WoT);

  dim3 g1(Mn / 128, Dn / 128, 3);
  k_gemm_qkv<<<g1, 512, 0, stream>>>(xb, WqT, WkT, WvT, bq, bk, bv, qb, kb, vtb);

  k_attn<<<(Sn / 128) * Bn * Hn, 256, 0, stream>>>(qb, kb, vtb, ctx);

  dim3 g3(Mn / 128, Dn / 128);
  k_gemm_out<<<g3, 512, 0, stream>>>(ctx, WoT, bo, out);
}

// Round 9
// 269.857 us; speedup vs baseline: 1.0353x; 1.0353x over previous
//
#include <hip/hip_runtime.h>

// MHA: B=4 S=2048 D=1024 H=16 DH=64. Full bf16-MFMA pipeline (fp32 accum).

#define Bn  4
#define Sn  2048
#define Dn  1024
#define Hn  16
#define DHn 64
#define Mn  (Bn*Sn)          // 8192 rows

typedef unsigned short u16;
typedef __attribute__((ext_vector_type(8))) short short8;   // 8 x bf16 (4 VGPRs)
typedef __attribute__((ext_vector_type(4))) float f32x4;    // MFMA C/D frag
typedef __attribute__((ext_vector_type(4))) unsigned int uint4v;

__device__ __forceinline__ u16 f2bf(float f) {
  unsigned u = __float_as_uint(f);
  return (u16)((u + 0x7FFFu + ((u >> 16) & 1u)) >> 16);   // RNE
}

// async 16B/lane global->LDS DMA; lds dest = wave-uniform base + lane*16
__device__ __forceinline__ void async16(const void* g, void* l) {
  __builtin_amdgcn_global_load_lds(
      (const __attribute__((address_space(1))) void*)g,
      (__attribute__((address_space(3))) void*)l, 16, 0, 0);
}

// pack 2 fp32 -> 2 bf16 (truncation) in one v_perm_b32
__device__ __forceinline__ unsigned pk2(float a, float b) {
  return __builtin_amdgcn_perm(__float_as_uint(b), __float_as_uint(a), 0x07060302u);
}

// ---------------- merged convert: x->bf16 (blocks 0..8191) + weights (8192..9215) ----------------
__global__ __launch_bounds__(256) void k_convert(
    const float4* __restrict__ x, ushort4* __restrict__ xb, int n4,
    const float* __restrict__ Wq, const float* __restrict__ Wk,
    const float* __restrict__ Wv, const float* __restrict__ Wo,
    u16* __restrict__ WqT, u16* __restrict__ WkT,
    u16* __restrict__ WvT, u16* __restrict__ WoT) {
  __shared__ float t[64][65];
  const int bid0 = blockIdx.x;
  if (bid0 < 8192) {
    int i = bid0 * 256 + threadIdx.x;
    if (i < n4) {
      float4 f = x[i];
      ushort4 o;
      o.x = f2bf(f.x); o.y = f2bf(f.y); o.z = f2bf(f.z); o.w = f2bf(f.w);
      xb[i] = o;
    }
    return;
  }
  const int bid = bid0 - 8192;         // 0..1023
  const int wsel = bid >> 8;           // 0..3
  const int idx = bid & 255;
  const int tid = threadIdx.x;
  const int c = tid & 63;
  const int r4 = tid >> 6;             // 0..3

  if (wsel < 3) {
    const float* W = (wsel == 0) ? Wq : (wsel == 1) ? Wk : Wv;
    u16* T = (wsel == 0) ? WqT : (wsel == 1) ? WkT : WvT;
    const int h = idx >> 4;
    const int d0 = (idx & 15) * 64;
    const float* src = W + (size_t)h * (Dn * DHn) + (size_t)d0 * DHn;
#pragma unroll
    for (int r = 0; r < 16; r++) {
      int row = r * 4 + r4;
      t[row][c] = src[row * DHn + c];
    }
    __syncthreads();
    u16* dst = T + (size_t)(h * 64) * Dn + d0;
#pragma unroll
    for (int r = 0; r < 16; r++) {
      int erow = r * 4 + r4;
      dst[(size_t)erow * Dn + c] = f2bf(t[c][erow]);
    }
  } else {
    const int n0 = (idx >> 4) * 64;
    const int d0 = (idx & 15) * 64;
#pragma unroll
    for (int r = 0; r < 16; r++) {
      int row = r * 4 + r4;
      t[row][c] = Wo[(size_t)(d0 + row) * Dn + n0 + c];
    }
    __syncthreads();
#pragma unroll
    for (int r = 0; r < 16; r++) {
      int nrow = r * 4 + r4;
      WoT[(size_t)(n0 + nrow) * Dn + d0 + c] = f2bf(t[c][nrow]);
    }
  }
}

// ---------------- QKV projection GEMM body: 512 thr / 8 waves, 128x128 tile ----------------
template<int SWAP>
__device__ __forceinline__ void qkv_body(
    u16* As, u16* Bs, const u16* __restrict__ A, const u16* __restrict__ BT,
    const float* __restrict__ bias, u16* __restrict__ dst, float scale,
    int tile_m, int tile_n) {
  const int K = Dn;
  const int tid = threadIdx.x;
  const int lane = tid & 63;
  const int wave = tid >> 6;                    // 0..7
  const int wm = wave & 3, wn = wave >> 2;
  const int quad = lane >> 4, l16 = lane & 15;
  const int srow8 = lane >> 3;
  const int gchunk = (lane & 7) ^ srow8;
  const int sw = l16 & 7;

  f32x4 acc[2][4];
#pragma unroll
  for (int i = 0; i < 2; i++)
#pragma unroll
    for (int j = 0; j < 4; j++) acc[i][j] = (f32x4){0.f, 0.f, 0.f, 0.f};

  for (int k0 = 0; k0 < K; k0 += 64) {
    const int rb = wave * 16;
    async16(&A[(size_t)(tile_m + rb + srow8) * K + k0 + gchunk * 8], &As[rb * 64]);
    async16(&A[(size_t)(tile_m + rb + 8 + srow8) * K + k0 + gchunk * 8], &As[(rb + 8) * 64]);
    async16(&BT[(size_t)(tile_n + rb + srow8) * K + k0 + gchunk * 8], &Bs[rb * 64]);
    async16(&BT[(size_t)(tile_n + rb + 8 + srow8) * K + k0 + gchunk * 8], &Bs[(rb + 8) * 64]);
    __syncthreads();
#pragma unroll
    for (int ks = 0; ks < 2; ++ks) {
      short8 a[2], b[4];
#pragma unroll
      for (int i = 0; i < 2; i++)
        a[i] = *(const short8*)&As[(wm * 32 + i * 16 + l16) * 64 + ((ks * 4 + quad) ^ sw) * 8];
#pragma unroll
      for (int j = 0; j < 4; j++)
        b[j] = *(const short8*)&Bs[(wn * 64 + j * 16 + l16) * 64 + ((ks * 4 + quad) ^ sw) * 8];
#pragma unroll
      for (int i = 0; i < 2; i++)
#pragma unroll
        for (int j = 0; j < 4; j++)
          acc[i][j] = SWAP
              ? __builtin_amdgcn_mfma_f32_16x16x32_bf16(b[j], a[i], acc[i][j], 0, 0, 0)
              : __builtin_amdgcn_mfma_f32_16x16x32_bf16(a[i], b[j], acc[i][j], 0, 0, 0);
    }
    __syncthreads();
  }

  if (SWAP) {
#pragma unroll
    for (int i = 0; i < 2; i++) {
      const int s = tile_m + wm * 32 + i * 16 + l16;
      const int bb = s >> 11, sl = s & 2047;
#pragma unroll
      for (int j = 0; j < 4; j++) {
        const int nb = tile_n + wn * 64 + j * 16 + quad * 4;
        const float4 b4 = *(const float4*)&bias[nb];
        const int h = nb >> 6, e0 = nb & 63;
        ushort4 o;
        o.x = f2bf((acc[i][j][0] + b4.x) * scale);
        o.y = f2bf((acc[i][j][1] + b4.y) * scale);
        o.z = f2bf((acc[i][j][2] + b4.z) * scale);
        o.w = f2bf((acc[i][j][3] + b4.w) * scale);
        *(ushort4*)&dst[((size_t)(bb * Hn + h) * Sn + sl) * DHn + e0] = o;
      }
    }
  } else {
#pragma unroll
    for (int i = 0; i < 2; i++) {
      const int s0 = tile_m + wm * 32 + i * 16 + quad * 4;
      const int bb = s0 >> 11, sl = s0 & 2047;
#pragma unroll
      for (int j = 0; j < 4; j++) {
        const int n = tile_n + wn * 64 + j * 16 + l16;
        const int h = n >> 6, e = n & 63;
        const float bn = bias[n];
        ushort4 o;
        o.x = f2bf(acc[i][j][0] + bn);
        o.y = f2bf(acc[i][j][1] + bn);
        o.z = f2bf(acc[i][j][2] + bn);
        o.w = f2bf(acc[i][j][3] + bn);
        *(ushort4*)&dst[((size_t)(bb * Hn + h) * DHn + e) * Sn + sl] = o;
      }
    }
  }
}

// single dispatch, z = 0(q) / 1(k) / 2(v); both epilogue styles preserved
__global__ __launch_bounds__(512) void k_gemm_qkv(
    const u16* __restrict__ A, const u16* __restrict__ WqT,
    const u16* __restrict__ WkT, const u16* __restrict__ WvT,
    const float* __restrict__ bq, const float* __restrict__ bk,
    const float* __restrict__ bv, u16* __restrict__ qb,
    u16* __restrict__ kb, u16* __restrict__ vtb) {
  __shared__ u16 As[128 * 64];
  __shared__ u16 Bs[128 * 64];
  const int tile_m = blockIdx.x * 128;
  const int tile_n = blockIdx.y * 128;
  const int z = blockIdx.z;
  if (z == 2) {
    qkv_body<0>(As, Bs, A, WvT, bv, vtb, 1.0f, tile_m, tile_n);
  } else if (z == 1) {
    qkv_body<1>(As, Bs, A, WkT, bk, kb, 1.0f, tile_m, tile_n);
  } else {
    qkv_body<1>(As, Bs, A, WqT, bq, qb, 0.18033688011112042f, tile_m, tile_n);
  }
}

// ---------------- flash attention (R8 + DMA-V) ----------------
// 4 waves x 32 q-rows, 64 keys/tile, XCD-local block decode, key-permuted K
// staging, ones-MFMA lr (all R6/R8-verified). NEW: V staged via
// global_load_lds with pre-swizzled source (chunk XOR row&7 == K's gchunk
// pattern since row base wave*16 is 0 mod 8); read side applies the same XOR
// ((P*4+quad)^(l16&7)) — both-sides swizzle. Removes per-tile V global loads,
// ds_writes, vv registers, and the LDKV pad (LDS 34.8 -> 32 KB).
__global__ __launch_bounds__(256) void k_attn(
    const u16* __restrict__ qg, const u16* __restrict__ kg,
    const u16* __restrict__ vg, u16* __restrict__ ctx) {
  const int p = blockIdx.x;                         // 0..1023
  const int logical = (p & 7) * 128 + (p >> 3);     // same-bh blocks -> same XCD
  const int bh = logical >> 4;
  const int b = bh >> 4, h = bh & 15;
  const int tid = threadIdx.x;
  const int wave = tid >> 6, lane = tid & 63;
  const int quad = lane >> 4, l16 = lane & 15;
  const int qbase = (logical & 15) * 128 + wave * 32;

  const u16* qp = qg + (size_t)bh * Sn * DHn;
  const u16* kp = kg + (size_t)bh * Sn * DHn;
  const u16* vp = vg + (size_t)bh * DHn * Sn;   // [DH][S]

  __shared__ u16 Ks[2][64 * 64];    // 16 KB
  __shared__ u16 Vs[2][64 * 64];    // 16 KB

  const int srow8 = lane >> 3;
  const int gchunk = (lane & 7) ^ srow8;
  const int sw = l16 & 7;
  const int rbase = wave * 16;

  // permuted key indices for this lane's two staged K rows (loop-invariant)
  const int r0 = rbase + srow8;
  const int r1 = r0 + 8;
  const int pk0 = ((r0 >> 5) << 5) | (((r0 >> 2) & 3) << 3) | ((r0 & 16) >> 2) | (r0 & 3);
  const int pk1 = ((r1 >> 5) << 5) | (((r1 >> 2) & 3) << 3) | ((r1 & 16) >> 2) | (r1 & 3);

  // V read chunk offsets (both-sides swizzle), per-lane constants
  const int vc0 = (quad ^ sw) * 8;          // P = 0
  const int vc1 = ((quad + 4) ^ sw) * 8;    // P = 1

  short8 bq[2][2];
#pragma unroll
  for (int g2 = 0; g2 < 2; g2++) {
    bq[g2][0] = *(const short8*)&qp[(size_t)(qbase + g2 * 16 + l16) * DHn + quad * 8];
    bq[g2][1] = *(const short8*)&qp[(size_t)(qbase + g2 * 16 + l16) * DHn + 32 + quad * 8];
  }

  f32x4 octx[2][4];
#pragma unroll
  for (int g2 = 0; g2 < 2; g2++)
#pragma unroll
    for (int j = 0; j < 4; j++) octx[g2][j] = (f32x4){0.f, 0.f, 0.f, 0.f};
  f32x4 octl[2];
  octl[0] = (f32x4){0.f, 0.f, 0.f, 0.f};
  octl[1] = (f32x4){0.f, 0.f, 0.f, 0.f};
  const short8 vones = {(short)0x3F80, (short)0x3F80, (short)0x3F80, (short)0x3F80,
                        (short)0x3F80, (short)0x3F80, (short)0x3F80, (short)0x3F80};

  // prologue: stage K,V tile 0 (DMA; V source pre-swizzled)
  async16(&kp[(size_t)pk0 * DHn + gchunk * 8], &Ks[0][rbase * 64]);
  async16(&kp[(size_t)pk1 * DHn + gchunk * 8], &Ks[0][(rbase + 8) * 64]);
  async16(&vp[(size_t)(rbase + srow8) * Sn + gchunk * 8], &Vs[0][rbase * 64]);
  async16(&vp[(size_t)(rbase + 8 + srow8) * Sn + gchunk * 8], &Vs[0][(rbase + 8) * 64]);
  __syncthreads();

  for (int kt = 0; kt < Sn / 64; ++kt) {
    const int cur = kt & 1, nxt = cur ^ 1;
    if (kt + 1 < Sn / 64) {
      const int key1 = (kt + 1) * 64;
      async16(&kp[(size_t)(key1 + pk0) * DHn + gchunk * 8], &Ks[nxt][rbase * 64]);
      async16(&kp[(size_t)(key1 + pk1) * DHn + gchunk * 8], &Ks[nxt][(rbase + 8) * 64]);
      async16(&vp[(size_t)(rbase + srow8) * Sn + key1 + gchunk * 8], &Vs[nxt][rbase * 64]);
      async16(&vp[(size_t)(rbase + 8 + srow8) * Sn + key1 + gchunk * 8], &Vs[nxt][(rbase + 8) * 64]);
    }

    // QK^T + exp2 + pack; groups g = 2P + half fill apv[g2][P] halves in-lane
    uint4v apv[2][2];
#pragma unroll
    for (int g = 0; g < 4; g++) {
      short8 ka0 = *(const short8*)&Ks[cur][(g * 16 + l16) * 64 + (quad ^ sw) * 8];
      short8 ka1 = *(const short8*)&Ks[cur][(g * 16 + l16) * 64 + ((quad + 4) ^ sw) * 8];
#pragma unroll
      for (int g2 = 0; g2 < 2; g2++) {
        f32x4 sc = (f32x4){0.f, 0.f, 0.f, 0.f};
        sc = __builtin_amdgcn_mfma_f32_16x16x32_bf16(ka0, bq[g2][0], sc, 0, 0, 0);
        sc = __builtin_amdgcn_mfma_f32_16x16x32_bf16(ka1, bq[g2][1], sc, 0, 0, 0);
        float p4[4];
#pragma unroll
        for (int r = 0; r < 4; r++) p4[r] = __builtin_amdgcn_exp2f(sc[r]);
        apv[g2][g >> 1][(g & 1) * 2]     = pk2(p4[0], p4[1]);
        apv[g2][g >> 1][(g & 1) * 2 + 1] = pk2(p4[2], p4[3]);
      }
    }

    // lr via ones-B MFMA (4x) + PV: 16x 16x16x32 MFMA, B = V short8 (b128)
#pragma unroll
    for (int P = 0; P < 2; P++) {
      octl[0] = __builtin_amdgcn_mfma_f32_16x16x32_bf16(
          __builtin_bit_cast(short8, apv[0][P]), vones, octl[0], 0, 0, 0);
      octl[1] = __builtin_amdgcn_mfma_f32_16x16x32_bf16(
          __builtin_bit_cast(short8, apv[1][P]), vones, octl[1], 0, 0, 0);
    }
#pragma unroll
    for (int j = 0; j < 4; j++) {
#pragma unroll
      for (int P = 0; P < 2; P++) {
        short8 vb = *(const short8*)&Vs[cur][(j * 16 + l16) * 64 + (P ? vc1 : vc0)];
        octx[0][j] = __builtin_amdgcn_mfma_f32_16x16x32_bf16(
            __builtin_bit_cast(short8, apv[0][P]), vb, octx[0][j], 0, 0, 0);
        octx[1][j] = __builtin_amdgcn_mfma_f32_16x16x32_bf16(
            __builtin_bit_cast(short8, apv[1][P]), vb, octx[1][j], 0, 0, 0);
      }
    }
    __syncthreads();                  // drains next-tile DMA; Ks/Vs[cur] reads done
  }

  // octl[g2][r] = lr for q-row qbase + g2*16 + quad*4 + r (same in all l16)
  float rl[2][4];
#pragma unroll
  for (int g2 = 0; g2 < 2; g2++)
#pragma unroll
    for (int r = 0; r < 4; r++)
      rl[g2][r] = 1.0f / octl[g2][r];

#pragma unroll
  for (int g2 = 0; g2 < 2; g2++)
#pragma unroll
    for (int j = 0; j < 4; j++) {
      const int n = h * DHn + j * 16 + l16;
#pragma unroll
      for (int r = 0; r < 4; r++) {
        const int s = qbase + g2 * 16 + quad * 4 + r;
        ctx[(size_t)(b * Sn + s) * Dn + n] = f2bf(octx[g2][j][r] * rl[g2][r]);
      }
    }
}

// ---------------- output projection GEMM: 512 thr / 8 waves, swapped epilogue ----------------
__global__ __launch_bounds__(512) void k_gemm_out(
    const u16* __restrict__ A, const u16* __restrict__ WoT,
    const float* __restrict__ bo, float* __restrict__ out) {
  const int tile_m = blockIdx.x * 128;
  const int tile_n = blockIdx.y * 128;
  const int K = Dn;

  __shared__ u16 As[128 * 64];
  __shared__ u16 Bs[128 * 64];

  const int tid = threadIdx.x;
  const int lane = tid & 63;
  const int wave = tid >> 6;
  const int wm = wave & 3, wn = wave >> 2;
  const int quad = lane >> 4, l16 = lane & 15;
  const int srow8 = lane >> 3;
  const int gchunk = (lane & 7) ^ srow8;
  const int sw = l16 & 7;

  f32x4 acc[2][4];
#pragma unroll
  for (int i = 0; i < 2; i++)
#pragma unroll
    for (int j = 0; j < 4; j++) acc[i][j] = (f32x4){0.f, 0.f, 0.f, 0.f};

  for (int k0 = 0; k0 < K; k0 += 64) {
    const int rb = wave * 16;
    async16(&A[(size_t)(tile_m + rb + srow8) * K + k0 + gchunk * 8], &As[rb * 64]);
    async16(&A[(size_t)(tile_m + rb + 8 + srow8) * K + k0 + gchunk * 8], &As[(rb + 8) * 64]);
    async16(&WoT[(size_t)(tile_n + rb + srow8) * K + k0 + gchunk * 8], &Bs[rb * 64]);
    async16(&WoT[(size_t)(tile_n + rb + 8 + srow8) * K + k0 + gchunk * 8], &Bs[(rb + 8) * 64]);
    __syncthreads();
#pragma unroll
    for (int ks = 0; ks < 2; ++ks) {
      short8 a[2], b[4];
#pragma unroll
      for (int i = 0; i < 2; i++)
        a[i] = *(const short8*)&As[(wm * 32 + i * 16 + l16) * 64 + ((ks * 4 + quad) ^ sw) * 8];
#pragma unroll
      for (int j = 0; j < 4; j++)
        b[j] = *(const short8*)&Bs[(wn * 64 + j * 16 + l16) * 64 + ((ks * 4 + quad) ^ sw) * 8];
#pragma unroll
      for (int i = 0; i < 2; i++)
#pragma unroll
        for (int j = 0; j < 4; j++)
          acc[i][j] = __builtin_amdgcn_mfma_f32_16x16x32_bf16(b[j], a[i], acc[i][j], 0, 0, 0);
    }
    __syncthreads();
  }

#pragma unroll
  for (int i = 0; i < 2; i++) {
    const int s = tile_m + wm * 32 + i * 16 + l16;
#pragma unroll
    for (int j = 0; j < 4; j++) {
      const int nb = tile_n + wn * 64 + j * 16 + quad * 4;
      const float4 b4 = *(const float4*)&bo[nb];
      float4 o;
      o.x = acc[i][j][0] + b4.x;
      o.y = acc[i][j][1] + b4.y;
      o.z = acc[i][j][2] + b4.z;
      o.w = acc[i][j][3] + b4.w;
      *(float4*)&out[(size_t)s * Dn + nb] = o;
    }
  }
}

extern "C" void kernel_launch(void* const* d_in, const int* in_sizes, int n_in,
                              void* d_out, int out_size, void* d_ws, size_t ws_size,
                              hipStream_t stream) {
  const float* x  = (const float*)d_in[0];
  const float* Wq = (const float*)d_in[1];
  const float* bq = (const float*)d_in[2];
  const float* Wk = (const float*)d_in[3];
  const float* bk = (const float*)d_in[4];
  const float* Wv = (const float*)d_in[5];
  const float* bv = (const float*)d_in[6];
  const float* Wo = (const float*)d_in[7];
  const float* bo = (const float*)d_in[8];
  float* out = (float*)d_out;

  // workspace carve-up (ctx aliases xb: xb dead after k_gemm_qkv) — ~75.5 MB
  char* ws = (char*)d_ws;
  u16* xb  = (u16*)ws;  ws += (size_t)Mn * Dn * 2;
  u16* WqT = (u16*)ws;  ws += (size_t)Dn * Dn * 2;
  u16* WkT = (u16*)ws;  ws += (size_t)Dn * Dn * 2;
  u16* WvT = (u16*)ws;  ws += (size_t)Dn * Dn * 2;
  u16* WoT = (u16*)ws;  ws += (size_t)Dn * Dn * 2;
  u16* qb  = (u16*)ws;  ws += (size_t)Mn * Dn * 2;
  u16* kb  = (u16*)ws;  ws += (size_t)Mn * Dn * 2;
  u16* vtb = (u16*)ws;  ws += (size_t)Mn * Dn * 2;
  u16* ctx = xb;        // alias

  k_convert<<<8192 + 1024, 256, 0, stream>>>(
      (const float4*)x, (ushort4*)xb, Mn * Dn / 4,
      Wq, Wk, Wv, Wo, WqT, WkT, WvT, WoT);

  dim3 g1(Mn / 128, Dn / 128, 3);
  k_gemm_qkv<<<g1, 512, 0, stream>>>(xb, WqT, WkT, WvT, bq, bk, bv, qb, kb, vtb);

  k_attn<<<(Sn / 128) * Bn * Hn, 256, 0, stream>>>(qb, kb, vtb, ctx);

  dim3 g3(Mn / 128, Dn / 128);
  k_gemm_out<<<g3, 512, 0, stream>>>(ctx, WoT, bo, out);
}

// Round 10
// 262.954 us; speedup vs baseline: 1.0625x; 1.0263x over previous
//
#include <hip/hip_runtime.h>

// MHA: B=4 S=2048 D=1024 H=16 DH=64. Full bf16-MFMA pipeline (fp32 accum).

#define Bn  4
#define Sn  2048
#define Dn  1024
#define Hn  16
#define DHn 64
#define Mn  (Bn*Sn)          // 8192 rows
#define LDKV 72              // attn V LDS row stride (ushorts)

typedef unsigned short u16;
typedef __attribute__((ext_vector_type(8))) short short8;   // 8 x bf16 (4 VGPRs)
typedef __attribute__((ext_vector_type(4))) float f32x4;    // MFMA C/D frag
typedef __attribute__((ext_vector_type(2))) unsigned int uint2v;
typedef __attribute__((ext_vector_type(4))) unsigned int uint4v;

__device__ __forceinline__ u16 f2bf(float f) {
  unsigned u = __float_as_uint(f);
  return (u16)((u + 0x7FFFu + ((u >> 16) & 1u)) >> 16);   // RNE
}

// async 16B/lane global->LDS DMA; lds dest = wave-uniform base + lane*16
__device__ __forceinline__ void async16(const void* g, void* l) {
  __builtin_amdgcn_global_load_lds(
      (const __attribute__((address_space(1))) void*)g,
      (__attribute__((address_space(3))) void*)l, 16, 0, 0);
}

// pack 2 fp32 -> 2 bf16 (truncation) in one v_perm_b32
__device__ __forceinline__ unsigned pk2(float a, float b) {
  return __builtin_amdgcn_perm(__float_as_uint(b), __float_as_uint(a), 0x07060302u);
}

// ---------------- merged convert: x->bf16 (blocks 0..8191) + weights (8192..9215) ----------------
__global__ __launch_bounds__(256) void k_convert(
    const float4* __restrict__ x, ushort4* __restrict__ xb, int n4,
    const float* __restrict__ Wq, const float* __restrict__ Wk,
    const float* __restrict__ Wv, const float* __restrict__ Wo,
    u16* __restrict__ WqT, u16* __restrict__ WkT,
    u16* __restrict__ WvT, u16* __restrict__ WoT) {
  __shared__ float t[64][65];
  const int bid0 = blockIdx.x;
  if (bid0 < 8192) {
    int i = bid0 * 256 + threadIdx.x;
    if (i < n4) {
      float4 f = x[i];
      ushort4 o;
      o.x = f2bf(f.x); o.y = f2bf(f.y); o.z = f2bf(f.z); o.w = f2bf(f.w);
      xb[i] = o;
    }
    return;
  }
  const int bid = bid0 - 8192;         // 0..1023
  const int wsel = bid >> 8;           // 0..3
  const int idx = bid & 255;
  const int tid = threadIdx.x;
  const int c = tid & 63;
  const int r4 = tid >> 6;             // 0..3

  if (wsel < 3) {
    const float* W = (wsel == 0) ? Wq : (wsel == 1) ? Wk : Wv;
    u16* T = (wsel == 0) ? WqT : (wsel == 1) ? WkT : WvT;
    const int h = idx >> 4;
    const int d0 = (idx & 15) * 64;
    const float* src = W + (size_t)h * (Dn * DHn) + (size_t)d0 * DHn;
#pragma unroll
    for (int r = 0; r < 16; r++) {
      int row = r * 4 + r4;
      t[row][c] = src[row * DHn + c];
    }
    __syncthreads();
    u16* dst = T + (size_t)(h * 64) * Dn + d0;
#pragma unroll
    for (int r = 0; r < 16; r++) {
      int erow = r * 4 + r4;
      dst[(size_t)erow * Dn + c] = f2bf(t[c][erow]);
    }
  } else {
    const int n0 = (idx >> 4) * 64;
    const int d0 = (idx & 15) * 64;
#pragma unroll
    for (int r = 0; r < 16; r++) {
      int row = r * 4 + r4;
      t[row][c] = Wo[(size_t)(d0 + row) * Dn + n0 + c];
    }
    __syncthreads();
#pragma unroll
    for (int r = 0; r < 16; r++) {
      int nrow = r * 4 + r4;
      WoT[(size_t)(n0 + nrow) * Dn + d0 + c] = f2bf(t[c][nrow]);
    }
  }
}

// ---------------- QKV projection GEMM body: 512 thr / 8 waves, 128x128 tile ----------------
template<int SWAP>
__device__ __forceinline__ void qkv_body(
    u16* As, u16* Bs, const u16* __restrict__ A, const u16* __restrict__ BT,
    const float* __restrict__ bias, u16* __restrict__ dst, float scale,
    int tile_m, int tile_n) {
  const int K = Dn;
  const int tid = threadIdx.x;
  const int lane = tid & 63;
  const int wave = tid >> 6;                    // 0..7
  const int wm = wave & 3, wn = wave >> 2;
  const int quad = lane >> 4, l16 = lane & 15;
  const int srow8 = lane >> 3;
  const int gchunk = (lane & 7) ^ srow8;
  const int sw = l16 & 7;

  f32x4 acc[2][4];
#pragma unroll
  for (int i = 0; i < 2; i++)
#pragma unroll
    for (int j = 0; j < 4; j++) acc[i][j] = (f32x4){0.f, 0.f, 0.f, 0.f};

  for (int k0 = 0; k0 < K; k0 += 64) {
    const int rb = wave * 16;
    async16(&A[(size_t)(tile_m + rb + srow8) * K + k0 + gchunk * 8], &As[rb * 64]);
    async16(&A[(size_t)(tile_m + rb + 8 + srow8) * K + k0 + gchunk * 8], &As[(rb + 8) * 64]);
    async16(&BT[(size_t)(tile_n + rb + srow8) * K + k0 + gchunk * 8], &Bs[rb * 64]);
    async16(&BT[(size_t)(tile_n + rb + 8 + srow8) * K + k0 + gchunk * 8], &Bs[(rb + 8) * 64]);
    __syncthreads();
#pragma unroll
    for (int ks = 0; ks < 2; ++ks) {
      short8 a[2], b[4];
#pragma unroll
      for (int i = 0; i < 2; i++)
        a[i] = *(const short8*)&As[(wm * 32 + i * 16 + l16) * 64 + ((ks * 4 + quad) ^ sw) * 8];
#pragma unroll
      for (int j = 0; j < 4; j++)
        b[j] = *(const short8*)&Bs[(wn * 64 + j * 16 + l16) * 64 + ((ks * 4 + quad) ^ sw) * 8];
#pragma unroll
      for (int i = 0; i < 2; i++)
#pragma unroll
        for (int j = 0; j < 4; j++)
          acc[i][j] = SWAP
              ? __builtin_amdgcn_mfma_f32_16x16x32_bf16(b[j], a[i], acc[i][j], 0, 0, 0)
              : __builtin_amdgcn_mfma_f32_16x16x32_bf16(a[i], b[j], acc[i][j], 0, 0, 0);
    }
    __syncthreads();
  }

  if (SWAP) {
#pragma unroll
    for (int i = 0; i < 2; i++) {
      const int s = tile_m + wm * 32 + i * 16 + l16;
      const int bb = s >> 11, sl = s & 2047;
#pragma unroll
      for (int j = 0; j < 4; j++) {
        const int nb = tile_n + wn * 64 + j * 16 + quad * 4;
        const float4 b4 = *(const float4*)&bias[nb];
        const int h = nb >> 6, e0 = nb & 63;
        ushort4 o;
        o.x = f2bf((acc[i][j][0] + b4.x) * scale);
        o.y = f2bf((acc[i][j][1] + b4.y) * scale);
        o.z = f2bf((acc[i][j][2] + b4.z) * scale);
        o.w = f2bf((acc[i][j][3] + b4.w) * scale);
        *(ushort4*)&dst[((size_t)(bb * Hn + h) * Sn + sl) * DHn + e0] = o;
      }
    }
  } else {
#pragma unroll
    for (int i = 0; i < 2; i++) {
      const int s0 = tile_m + wm * 32 + i * 16 + quad * 4;
      const int bb = s0 >> 11, sl = s0 & 2047;
#pragma unroll
      for (int j = 0; j < 4; j++) {
        const int n = tile_n + wn * 64 + j * 16 + l16;
        const int h = n >> 6, e = n & 63;
        const float bn = bias[n];
        ushort4 o;
        o.x = f2bf(acc[i][j][0] + bn);
        o.y = f2bf(acc[i][j][1] + bn);
        o.z = f2bf(acc[i][j][2] + bn);
        o.w = f2bf(acc[i][j][3] + bn);
        *(ushort4*)&dst[((size_t)(bb * Hn + h) * DHn + e) * Sn + sl] = o;
      }
    }
  }
}

// 1-D grid (1536), XCD-local decode: xcd = p&7 owns 8 consecutive m-tiles
// (A-slice 2MB L2-resident); within XCD, (z,n) panels swept with each B panel
// (256KB) reused by 8 m-tiles back-to-back. R4-verified decode pattern.
__global__ __launch_bounds__(512) void k_gemm_qkv(
    const u16* __restrict__ A, const u16* __restrict__ WqT,
    const u16* __restrict__ WkT, const u16* __restrict__ WvT,
    const float* __restrict__ bq, const float* __restrict__ bk,
    const float* __restrict__ bv, u16* __restrict__ qb,
    u16* __restrict__ kb, u16* __restrict__ vtb) {
  __shared__ u16 As[128 * 64];
  __shared__ u16 Bs[128 * 64];
  const int p = blockIdx.x;            // 0..1535
  const int i = p >> 3;                // 0..191
  const int mt = (p & 7) * 8 + (i & 7);
  const int zn = i >> 3;               // 0..23
  const int z = zn >> 3;               // 0..2
  const int tile_m = mt * 128;
  const int tile_n = (zn & 7) * 128;
  if (z == 2) {
    qkv_body<0>(As, Bs, A, WvT, bv, vtb, 1.0f, tile_m, tile_n);
  } else if (z == 1) {
    qkv_body<1>(As, Bs, A, WkT, bk, kb, 1.0f, tile_m, tile_n);
  } else {
    qkv_body<1>(As, Bs, A, WqT, bq, qb, 0.18033688011112042f, tile_m, tile_n);
  }
}

// ---------------- flash attention (R8 config: reg-staged V, ones-MFMA lr) ----------------
// 4 waves x 32 q-rows, 64 keys/tile, XCD-local block decode, key-permuted K
// staging (PV = 16x 16x16x32 MFMA, in-lane A-fragment), ones-MFMA lr.
// V is reg-staged (global->reg early, LDS write late): R9 proved DMA-V is 6%
// SLOWER despite zero bank conflicts (conflicts are hidden; barrier vmcnt
// drain of 4 DMAs/wave is not). Keep reg-staged + LDKV pad.
__global__ __launch_bounds__(256) void k_attn(
    const u16* __restrict__ qg, const u16* __restrict__ kg,
    const u16* __restrict__ vg, u16* __restrict__ ctx) {
  const int p = blockIdx.x;                         // 0..1023
  const int logical = (p & 7) * 128 + (p >> 3);     // same-bh blocks -> same XCD
  const int bh = logical >> 4;
  const int b = bh >> 4, h = bh & 15;
  const int tid = threadIdx.x;
  const int wave = tid >> 6, lane = tid & 63;
  const int quad = lane >> 4, l16 = lane & 15;
  const int qbase = (logical & 15) * 128 + wave * 32;

  const u16* qp = qg + (size_t)bh * Sn * DHn;
  const u16* kp = kg + (size_t)bh * Sn * DHn;
  const u16* vp = vg + (size_t)bh * DHn * Sn;   // [DH][S]

  __shared__ u16 Ks[2][64 * 64];
  __shared__ u16 Vs[2][64 * LDKV];

  const int srow8 = lane >> 3;
  const int gchunk = (lane & 7) ^ srow8;
  const int sw = l16 & 7;

  const int vrow = tid >> 3;
  const int vc = tid & 7;

  // permuted key indices for this lane's two staged K rows (loop-invariant)
  const int r0 = wave * 16 + srow8;
  const int r1 = r0 + 8;
  const int pk0 = ((r0 >> 5) << 5) | (((r0 >> 2) & 3) << 3) | ((r0 & 16) >> 2) | (r0 & 3);
  const int pk1 = ((r1 >> 5) << 5) | (((r1 >> 2) & 3) << 3) | ((r1 & 16) >> 2) | (r1 & 3);

  short8 bq[2][2];
#pragma unroll
  for (int g2 = 0; g2 < 2; g2++) {
    bq[g2][0] = *(const short8*)&qp[(size_t)(qbase + g2 * 16 + l16) * DHn + quad * 8];
    bq[g2][1] = *(const short8*)&qp[(size_t)(qbase + g2 * 16 + l16) * DHn + 32 + quad * 8];
  }

  f32x4 octx[2][4];
#pragma unroll
  for (int g2 = 0; g2 < 2; g2++)
#pragma unroll
    for (int j = 0; j < 4; j++) octx[g2][j] = (f32x4){0.f, 0.f, 0.f, 0.f};
  f32x4 octl[2];
  octl[0] = (f32x4){0.f, 0.f, 0.f, 0.f};
  octl[1] = (f32x4){0.f, 0.f, 0.f, 0.f};
  const short8 vones = {(short)0x3F80, (short)0x3F80, (short)0x3F80, (short)0x3F80,
                        (short)0x3F80, (short)0x3F80, (short)0x3F80, (short)0x3F80};

  {
    const int rbase = wave * 16;
    async16(&kp[(size_t)pk0 * DHn + gchunk * 8], &Ks[0][rbase * 64]);
    async16(&kp[(size_t)pk1 * DHn + gchunk * 8], &Ks[0][(rbase + 8) * 64]);
    uint4 vv0 = *(const uint4*)&vp[(size_t)vrow * Sn + vc * 8];
    uint4 vv1 = *(const uint4*)&vp[(size_t)(32 + vrow) * Sn + vc * 8];
    *(uint4*)&Vs[0][vrow * LDKV + vc * 8] = vv0;
    *(uint4*)&Vs[0][(32 + vrow) * LDKV + vc * 8] = vv1;
  }
  __syncthreads();

  uint4 vv0, vv1;
  for (int kt = 0; kt < Sn / 64; ++kt) {
    const int cur = kt & 1, nxt = cur ^ 1;
    const bool more = (kt + 1 < Sn / 64);
    if (more) {
      const int key1 = (kt + 1) * 64;
      const int rbase = wave * 16;
      async16(&kp[(size_t)(key1 + pk0) * DHn + gchunk * 8], &Ks[nxt][rbase * 64]);
      async16(&kp[(size_t)(key1 + pk1) * DHn + gchunk * 8], &Ks[nxt][(rbase + 8) * 64]);
      vv0 = *(const uint4*)&vp[(size_t)vrow * Sn + key1 + vc * 8];
      vv1 = *(const uint4*)&vp[(size_t)(32 + vrow) * Sn + key1 + vc * 8];
    }

    // QK^T + exp2 + pack; groups g = 2P + half fill apv[g2][P] halves in-lane
    uint4v apv[2][2];
#pragma unroll
    for (int g = 0; g < 4; g++) {
      short8 ka0 = *(const short8*)&Ks[cur][(g * 16 + l16) * 64 + (quad ^ sw) * 8];
      short8 ka1 = *(const short8*)&Ks[cur][(g * 16 + l16) * 64 + ((quad + 4) ^ sw) * 8];
#pragma unroll
      for (int g2 = 0; g2 < 2; g2++) {
        f32x4 sc = (f32x4){0.f, 0.f, 0.f, 0.f};
        sc = __builtin_amdgcn_mfma_f32_16x16x32_bf16(ka0, bq[g2][0], sc, 0, 0, 0);
        sc = __builtin_amdgcn_mfma_f32_16x16x32_bf16(ka1, bq[g2][1], sc, 0, 0, 0);
        float p4[4];
#pragma unroll
        for (int r = 0; r < 4; r++) p4[r] = __builtin_amdgcn_exp2f(sc[r]);
        apv[g2][g >> 1][(g & 1) * 2]     = pk2(p4[0], p4[1]);
        apv[g2][g >> 1][(g & 1) * 2 + 1] = pk2(p4[2], p4[3]);
      }
    }

    // lr via ones-B MFMA (4x) + PV: 16x 16x16x32 MFMA, B = V short8 (b128)
#pragma unroll
    for (int P = 0; P < 2; P++) {
      octl[0] = __builtin_amdgcn_mfma_f32_16x16x32_bf16(
          __builtin_bit_cast(short8, apv[0][P]), vones, octl[0], 0, 0, 0);
      octl[1] = __builtin_amdgcn_mfma_f32_16x16x32_bf16(
          __builtin_bit_cast(short8, apv[1][P]), vones, octl[1], 0, 0, 0);
    }
#pragma unroll
    for (int j = 0; j < 4; j++) {
#pragma unroll
      for (int P = 0; P < 2; P++) {
        short8 vb = *(const short8*)&Vs[cur][(j * 16 + l16) * LDKV + P * 32 + quad * 8];
        octx[0][j] = __builtin_amdgcn_mfma_f32_16x16x32_bf16(
            __builtin_bit_cast(short8, apv[0][P]), vb, octx[0][j], 0, 0, 0);
        octx[1][j] = __builtin_amdgcn_mfma_f32_16x16x32_bf16(
            __builtin_bit_cast(short8, apv[1][P]), vb, octx[1][j], 0, 0, 0);
      }
    }

    if (more) {
      *(uint4*)&Vs[nxt][vrow * LDKV + vc * 8] = vv0;
      *(uint4*)&Vs[nxt][(32 + vrow) * LDKV + vc * 8] = vv1;
    }
    __syncthreads();
  }

  // octl[g2][r] = lr for q-row qbase + g2*16 + quad*4 + r (same in all l16)
  float rl[2][4];
#pragma unroll
  for (int g2 = 0; g2 < 2; g2++)
#pragma unroll
    for (int r = 0; r < 4; r++)
      rl[g2][r] = 1.0f / octl[g2][r];

#pragma unroll
  for (int g2 = 0; g2 < 2; g2++)
#pragma unroll
    for (int j = 0; j < 4; j++) {
      const int n = h * DHn + j * 16 + l16;
#pragma unroll
      for (int r = 0; r < 4; r++) {
        const int s = qbase + g2 * 16 + quad * 4 + r;
        ctx[(size_t)(b * Sn + s) * Dn + n] = f2bf(octx[g2][j][r] * rl[g2][r]);
      }
    }
}

// ---------------- output projection GEMM: 1-D grid (512), XCD-local decode ----------------
__global__ __launch_bounds__(512) void k_gemm_out(
    const u16* __restrict__ A, const u16* __restrict__ WoT,
    const float* __restrict__ bo, float* __restrict__ out) {
  const int p = blockIdx.x;            // 0..511
  const int i0 = p >> 3;               // 0..63
  const int tile_m = ((p & 7) * 8 + (i0 & 7)) * 128;
  const int tile_n = (i0 >> 3) * 128;
  const int K = Dn;

  __shared__ u16 As[128 * 64];
  __shared__ u16 Bs[128 * 64];

  const int tid = threadIdx.x;
  const int lane = tid & 63;
  const int wave = tid >> 6;
  const int wm = wave & 3, wn = wave >> 2;
  const int quad = lane >> 4, l16 = lane & 15;
  const int srow8 = lane >> 3;
  const int gchunk = (lane & 7) ^ srow8;
  const int sw = l16 & 7;

  f32x4 acc[2][4];
#pragma unroll
  for (int i = 0; i < 2; i++)
#pragma unroll
    for (int j = 0; j < 4; j++) acc[i][j] = (f32x4){0.f, 0.f, 0.f, 0.f};

  for (int k0 = 0; k0 < K; k0 += 64) {
    const int rb = wave * 16;
    async16(&A[(size_t)(tile_m + rb + srow8) * K + k0 + gchunk * 8], &As[rb * 64]);
    async16(&A[(size_t)(tile_m + rb + 8 + srow8) * K + k0 + gchunk * 8], &As[(rb + 8) * 64]);
    async16(&WoT[(size_t)(tile_n + rb + srow8) * K + k0 + gchunk * 8], &Bs[rb * 64]);
    async16(&WoT[(size_t)(tile_n + rb + 8 + srow8) * K + k0 + gchunk * 8], &Bs[(rb + 8) * 64]);
    __syncthreads();
#pragma unroll
    for (int ks = 0; ks < 2; ++ks) {
      short8 a[2], b[4];
#pragma unroll
      for (int i = 0; i < 2; i++)
        a[i] = *(const short8*)&As[(wm * 32 + i * 16 + l16) * 64 + ((ks * 4 + quad) ^ sw) * 8];
#pragma unroll
      for (int j = 0; j < 4; j++)
        b[j] = *(const short8*)&Bs[(wn * 64 + j * 16 + l16) * 64 + ((ks * 4 + quad) ^ sw) * 8];
#pragma unroll
      for (int i = 0; i < 2; i++)
#pragma unroll
        for (int j = 0; j < 4; j++)
          acc[i][j] = __builtin_amdgcn_mfma_f32_16x16x32_bf16(b[j], a[i], acc[i][j], 0, 0, 0);
    }
    __syncthreads();
  }

#pragma unroll
  for (int i = 0; i < 2; i++) {
    const int s = tile_m + wm * 32 + i * 16 + l16;
#pragma unroll
    for (int j = 0; j < 4; j++) {
      const int nb = tile_n + wn * 64 + j * 16 + quad * 4;
      const float4 b4 = *(const float4*)&bo[nb];
      float4 o;
      o.x = acc[i][j][0] + b4.x;
      o.y = acc[i][j][1] + b4.y;
      o.z = acc[i][j][2] + b4.z;
      o.w = acc[i][j][3] + b4.w;
      *(float4*)&out[(size_t)s * Dn + nb] = o;
    }
  }
}

extern "C" void kernel_launch(void* const* d_in, const int* in_sizes, int n_in,
                              void* d_out, int out_size, void* d_ws, size_t ws_size,
                              hipStream_t stream) {
  const float* x  = (const float*)d_in[0];
  const float* Wq = (const float*)d_in[1];
  const float* bq = (const float*)d_in[2];
  const float* Wk = (const float*)d_in[3];
  const float* bk = (const float*)d_in[4];
  const float* Wv = (const float*)d_in[5];
  const float* bv = (const float*)d_in[6];
  const float* Wo = (const float*)d_in[7];
  const float* bo = (const float*)d_in[8];
  float* out = (float*)d_out;

  // workspace carve-up (ctx aliases xb: xb dead after k_gemm_qkv) — ~75.5 MB
  char* ws = (char*)d_ws;
  u16* xb  = (u16*)ws;  ws += (size_t)Mn * Dn * 2;
  u16* WqT = (u16*)ws;  ws += (size_t)Dn * Dn * 2;
  u16* WkT = (u16*)ws;  ws += (size_t)Dn * Dn * 2;
  u16* WvT = (u16*)ws;  ws += (size_t)Dn * Dn * 2;
  u16* WoT = (u16*)ws;  ws += (size_t)Dn * Dn * 2;
  u16* qb  = (u16*)ws;  ws += (size_t)Mn * Dn * 2;
  u16* kb  = (u16*)ws;  ws += (size_t)Mn * Dn * 2;
  u16* vtb = (u16*)ws;  ws += (size_t)Mn * Dn * 2;
  u16* ctx = xb;        // alias

  k_convert<<<8192 + 1024, 256, 0, stream>>>(
      (const float4*)x, (ushort4*)xb, Mn * Dn / 4,
      Wq, Wk, Wv, Wo, WqT, WkT, WvT, WoT);

  k_gemm_qkv<<<(Mn / 128) * (Dn / 128) * 3, 512, 0, stream>>>(
      xb, WqT, WkT, WvT, bq, bk, bv, qb, kb, vtb);

  k_attn<<<(Sn / 128) * Bn * Hn, 256, 0, stream>>>(qb, kb, vtb, ctx);

  k_gemm_out<<<(Mn / 128) * (Dn / 128), 512, 0, stream>>>(ctx, WoT, bo, out);
}